// Round 14
// baseline (645.261 us; speedup 1.0000x reference)
//
#include <hip/hip_runtime.h>

#define NN 100000
#define EE 1600000
#define DIN 512
#define DH 256
#define DOUT 32
#define HNR 25
#define HNS 16
#define RBH 4000      // NN/HNR bins per range
#define HES 100000    // EE/HNS edges per slice
#define HISTB (HNR*HNS)

typedef _Float16 h16x8 __attribute__((ext_vector_type(8)));
typedef _Float16 h16x4 __attribute__((ext_vector_type(4)));
typedef float f32x4 __attribute__((ext_vector_type(4)));

union HU { unsigned int u; _Float16 h[2]; };

// ---------- weight transpose + fp16 convert ----------
__global__ __launch_bounds__(256) void conv_w1(const float* __restrict__ W1, _Float16* __restrict__ W1T){
  int i = blockIdx.x*256 + threadIdx.x;
  if (i < DIN*DH){
    int c = i >> 9, k = i & 511;          // W1T[c][k] = W1[k][c]
    W1T[i] = (_Float16)W1[k*DH + c];
  }
}
__global__ __launch_bounds__(256) void conv_w2(const float* __restrict__ W2, _Float16* __restrict__ W2T){
  int i = blockIdx.x*256 + threadIdx.x;
  if (i < DH*DOUT){
    int c = i >> 8, k = i & 255;          // W2T[c][k] = W2[k][c]
    W2T[i] = (_Float16)W2[k*DOUT + c];
  }
}

// ---------- fused1: src-hist + dst-hist (LDS bins, zero global atomics) + LDS gemm1 ----------
__global__ __launch_bounds__(256) void gemm1_hist(
    const float* __restrict__ feats, const _Float16* __restrict__ W1T,
    const float* __restrict__ b1, float* __restrict__ h1,
    const int* __restrict__ src, const int* __restrict__ dst,
    int* __restrict__ pO, int* __restrict__ pI)
{
  __shared__ __align__(16) int smem[RBH];          // 16000 B; gemm aliases 15360 B of it
  const int bid = blockIdx.x;
  const int tid = threadIdx.x;

  if (bid < 2*HISTB){
    const int hb = (bid < HISTB) ? bid : bid - HISTB;
    const int* keys = (bid < HISTB) ? src : dst;
    int* part = (bid < HISTB) ? pO : pI;
    const int r = hb / HNS, s = hb % HNS;
    const int r0 = r * RBH;
    for (int j = tid; j < RBH; j += 256) smem[j] = 0;
    __syncthreads();
    const int4* s4 = reinterpret_cast<const int4*>(keys + (size_t)s*HES);
    for (int i = tid; i < HES/8; i += 256){
      int4 a = s4[2*i], b = s4[2*i+1];
      int k;
      k = a.x - r0; if ((unsigned)k < RBH) atomicAdd(&smem[k], 1);
      k = a.y - r0; if ((unsigned)k < RBH) atomicAdd(&smem[k], 1);
      k = a.z - r0; if ((unsigned)k < RBH) atomicAdd(&smem[k], 1);
      k = a.w - r0; if ((unsigned)k < RBH) atomicAdd(&smem[k], 1);
      k = b.x - r0; if ((unsigned)k < RBH) atomicAdd(&smem[k], 1);
      k = b.y - r0; if ((unsigned)k < RBH) atomicAdd(&smem[k], 1);
      k = b.z - r0; if ((unsigned)k < RBH) atomicAdd(&smem[k], 1);
      k = b.w - r0; if ((unsigned)k < RBH) atomicAdd(&smem[k], 1);
    }
    __syncthreads();
    for (int j = tid; j < RBH; j += 256) part[(size_t)s*NN + r0 + j] = smem[j];
    return;
  }

  // ---- gemm1 (R3 engine), LDS aliased onto smem ----
  _Float16 (*At)[40] = reinterpret_cast<_Float16(*)[40]>(smem);
  _Float16 (*Bt)[40] = reinterpret_cast<_Float16(*)[40]>(reinterpret_cast<char*>(smem) + 5120);
  const int gid  = bid - 2*HISTB;
  const int col0 = (gid & 1) * 128;
  const int row0 = (gid >> 1) * 64;

  const int lane = tid & 63, wave = tid >> 6;
  const int wr = wave >> 1, wc = wave & 1;
  const int l15 = lane & 15, kg = lane >> 4;
  const int arow = tid >> 2, aseg = (tid & 3) * 8;
  const int bcol = tid >> 1, bseg = (tid & 1) * 16;
  const bool aok = (row0 + arow) < NN;
  const float* aP = feats + (size_t)(row0+arow)*DIN + aseg;
  const _Float16* bP = W1T + (size_t)(col0+bcol)*DIN + bseg;

  f32x4 acc[2][4];
#pragma unroll
  for (int m=0;m<2;m++)
#pragma unroll
    for (int n=0;n<4;n++){ acc[m][n][0]=0.f; acc[m][n][1]=0.f; acc[m][n][2]=0.f; acc[m][n][3]=0.f; }

  float4 fa0 = make_float4(0,0,0,0), fa1 = make_float4(0,0,0,0);
  h16x8 fb0, fb1;
  if (aok){
    fa0 = *reinterpret_cast<const float4*>(aP);
    fa1 = *reinterpret_cast<const float4*>(aP + 4);
  }
  fb0 = *reinterpret_cast<const h16x8*>(bP);
  fb1 = *reinterpret_cast<const h16x8*>(bP + 8);

  for (int t=0; t<16; ++t){
    {
      h16x4 v0, v1;
      v0[0]=(_Float16)fa0.x; v0[1]=(_Float16)fa0.y; v0[2]=(_Float16)fa0.z; v0[3]=(_Float16)fa0.w;
      v1[0]=(_Float16)fa1.x; v1[1]=(_Float16)fa1.y; v1[2]=(_Float16)fa1.z; v1[3]=(_Float16)fa1.w;
      *reinterpret_cast<h16x4*>(&At[arow][aseg])   = v0;
      *reinterpret_cast<h16x4*>(&At[arow][aseg+4]) = v1;
      *reinterpret_cast<h16x8*>(&Bt[bcol][bseg])   = fb0;
      *reinterpret_cast<h16x8*>(&Bt[bcol][bseg+8]) = fb1;
    }
    __syncthreads();
    if (t < 15){
      int k0 = (t+1)*32;
      if (aok){
        fa0 = *reinterpret_cast<const float4*>(aP + k0);
        fa1 = *reinterpret_cast<const float4*>(aP + k0 + 4);
      }
      fb0 = *reinterpret_cast<const h16x8*>(bP + k0);
      fb1 = *reinterpret_cast<const h16x8*>(bP + k0 + 8);
    }
    h16x8 af[2], bfr[4];
#pragma unroll
    for (int m=0;m<2;m++) af[m]  = *reinterpret_cast<const h16x8*>(&At[wr*32 + m*16 + l15][kg*8]);
#pragma unroll
    for (int n=0;n<4;n++) bfr[n] = *reinterpret_cast<const h16x8*>(&Bt[wc*64 + n*16 + l15][kg*8]);
#pragma unroll
    for (int m=0;m<2;m++)
#pragma unroll
      for (int n=0;n<4;n++)
        acc[m][n] = __builtin_amdgcn_mfma_f32_16x16x32_f16(af[m], bfr[n], acc[m][n], 0, 0, 0);
    __syncthreads();
  }
  const int rb = kg*4;
#pragma unroll
  for (int n=0;n<4;n++){
    int col = col0 + wc*64 + n*16 + l15;
    float bias = b1[col];
#pragma unroll
    for (int m=0;m<2;m++){
#pragma unroll
      for (int j=0;j<4;j++){
        int g = row0 + wr*32 + m*16 + rb + j;
        if (g < NN) h1[(size_t)g*DH + col] = acc[m][n][j] + bias;
      }
    }
  }
}

// ---------- combine: pO sums -> nS; pI -> per-(node,slice) exclusive bases; degI, nD ----------
__global__ __launch_bounds__(256) void combine(
    const int* __restrict__ pO, int* __restrict__ pI,
    int* __restrict__ degI, float* __restrict__ nS, float* __restrict__ nD)
{
  int v = blockIdx.x*256 + threadIdx.x;
  if (v >= NN) return;
  int so = 0;
#pragma unroll
  for (int s=0;s<HNS;s++) so += pO[(size_t)s*NN + v];
  int si = 0;
#pragma unroll
  for (int s=0;s<HNS;s++){
    int c = pI[(size_t)s*NN + v];
    pI[(size_t)s*NN + v] = si;
    si += c;
  }
  degI[v] = si;
  nS[v] = rsqrtf((float)(so > 0 ? so : 1));
  nD[v] = rsqrtf((float)(si > 0 ? si : 1));
}

// ---------- scans (offs = exclusive prefix of degI) ----------
__global__ __launch_bounds__(1024) void scan1(const int* __restrict__ degI, int* __restrict__ offs, int* __restrict__ bsum){
  __shared__ int sm[1024];
  int t = threadIdx.x;
  int g = blockIdx.x*1024 + t;
  int v = (g < NN) ? degI[g] : 0;
  sm[t] = v; __syncthreads();
  for (int o=1;o<1024;o<<=1){
    int a = (t>=o)? sm[t-o] : 0;
    __syncthreads();
    sm[t] += a;
    __syncthreads();
  }
  if (g < NN) offs[g] = sm[t] - v;
  if (t == 1023) bsum[blockIdx.x] = sm[t];
}
__global__ __launch_bounds__(128) void scan2(const int* __restrict__ bsum, int* __restrict__ boff, int nb){
  __shared__ int sm[128];
  int t = threadIdx.x;
  int v = (t < nb)? bsum[t] : 0;
  sm[t] = v; __syncthreads();
  for (int o=1;o<128;o<<=1){
    int a = (t>=o)? sm[t-o] : 0;
    __syncthreads();
    sm[t] += a;
    __syncthreads();
  }
  if (t < nb) boff[t] = sm[t] - v;
}
__global__ __launch_bounds__(256) void scan3(int* __restrict__ offs, const int* __restrict__ boff){
  int i = blockIdx.x*256 + threadIdx.x;
  if (i < NN) offs[i] += boff[i >> 10];
}

// ---------- fused2: LDS-cursor CSR scatter (zero global atomics) + LDS-free GEMM2 ----------
__global__ __launch_bounds__(256) void fused2(
    const float* __restrict__ h1, const _Float16* __restrict__ W2T,
    const float* __restrict__ b2, const float* __restrict__ nS,
    _Float16* __restrict__ h0h, _Float16* __restrict__ hsh,
    const int* __restrict__ src, const int* __restrict__ dst,
    const int* __restrict__ pI, const int* __restrict__ offs,
    int* __restrict__ csrc)
{
  __shared__ int cur[RBH];
  const int bid = blockIdx.x;
  const int tid = threadIdx.x;
  if (bid < HISTB){
    const int r = bid / HNS, s = bid % HNS;
    const int r0 = r * RBH;
    for (int j = tid; j < RBH; j += 256)
      cur[j] = pI[(size_t)s*NN + r0 + j] + offs[r0 + j];
    __syncthreads();
    const int e0 = s * HES, e1 = e0 + HES;
    for (int i = e0 + tid; i < e1; i += 256){
      int d = dst[i] - r0;
      if ((unsigned)d < RBH){
        int pos = atomicAdd(&cur[d], 1);              // LDS atomic only
        csrc[pos] = src[i];
      }
    }
    return;
  }
  const int gid = bid - HISTB;
  const int row0 = gid * 256;
  const int lane = tid & 63, wave = tid >> 6;
  const int l15 = lane & 15, kg = lane >> 4;

  f32x4 acc[4][2];
#pragma unroll
  for (int m=0;m<4;m++)
#pragma unroll
    for (int n=0;n<2;n++){ acc[m][n][0]=0.f; acc[m][n][1]=0.f; acc[m][n][2]=0.f; acc[m][n][3]=0.f; }

  const float* aP[4]; bool aok[4];
#pragma unroll
  for (int m=0;m<4;m++){
    int r = row0 + wave*64 + m*16 + l15;
    aok[m] = (r < NN);
    aP[m] = h1 + (size_t)r*DH + kg*8;
  }
  const _Float16* bP[2];
#pragma unroll
  for (int n=0;n<2;n++)
    bP[n] = W2T + (size_t)(n*16 + l15)*DH + kg*8;

  for (int t=0; t<8; ++t){
    const int k0 = t*32;
    h16x8 bf[2], af[4];
#pragma unroll
    for (int n=0;n<2;n++) bf[n] = *reinterpret_cast<const h16x8*>(bP[n] + k0);
#pragma unroll
    for (int m=0;m<4;m++){
      float4 x = make_float4(0,0,0,0), y = make_float4(0,0,0,0);
      if (aok[m]){
        x = *reinterpret_cast<const float4*>(aP[m] + k0);
        y = *reinterpret_cast<const float4*>(aP[m] + k0 + 4);
      }
      h16x8 v;
      v[0]=(_Float16)fmaxf(x.x,0.f); v[1]=(_Float16)fmaxf(x.y,0.f);
      v[2]=(_Float16)fmaxf(x.z,0.f); v[3]=(_Float16)fmaxf(x.w,0.f);
      v[4]=(_Float16)fmaxf(y.x,0.f); v[5]=(_Float16)fmaxf(y.y,0.f);
      v[6]=(_Float16)fmaxf(y.z,0.f); v[7]=(_Float16)fmaxf(y.w,0.f);
      af[m] = v;
    }
#pragma unroll
    for (int m=0;m<4;m++)
#pragma unroll
      for (int n=0;n<2;n++)
        acc[m][n] = __builtin_amdgcn_mfma_f32_16x16x32_f16(af[m], bf[n], acc[m][n], 0, 0, 0);
  }
  const int rb = kg*4;
#pragma unroll
  for (int n=0;n<2;n++){
    int col = n*16 + l15;
    float bias = b2[col];
#pragma unroll
    for (int m=0;m<4;m++){
#pragma unroll
      for (int j=0;j<4;j++){
        int g = row0 + wave*64 + m*16 + rb + j;
        if (g < NN){
          float val = acc[m][n][j] + bias;
          h0h[(size_t)g*DOUT + col] = (_Float16)val;
          hsh[(size_t)g*DOUT + col] = (_Float16)(nS[g] * val);
        }
      }
    }
  }
}

// ---------- prop: dwordx4 gather — 4 nodes x 4 slots x 4 feature-quads (~24us/iter) ----------
template<bool LAST>
__global__ __launch_bounds__(256) void propC(
    const uint4* __restrict__ hs, const uint4* __restrict__ h0,
    uint4* __restrict__ hs_out, float4* __restrict__ out4,
    const int* __restrict__ offs, const int* __restrict__ degI,
    const int* __restrict__ csrc,
    const float* __restrict__ nS, const float* __restrict__ nD)
{
  const int nw = gridDim.x * 4;
  const int wid = (blockIdx.x*256 + threadIdx.x) >> 6;
  const int lane = threadIdx.x & 63;
  const int n = lane >> 4;        // node in quad (bits 5:4)
  const int s = (lane >> 2) & 3;  // edge slot    (bits 3:2)
  const int q = lane & 3;         // feature quad (bits 1:0) -> 16B of row

  const int NQ = (NN + 3) / 4;
  for (int vq = wid; vq < NQ; vq += nw){
    const int v = vq*4 + n;
    const bool vok = (v < NN);
    int beg = 0, cnt = 0;
    if (vok){ beg = offs[v]; cnt = degI[v]; }
    float a[8];
#pragma unroll
    for (int k=0;k<8;k++) a[k]=0.f;

    int i = s;
    int e = (i < cnt) ? csrc[beg + i] : -1;
    while (__any(e >= 0)){
      int i2 = i + 4;
      int e2 = (i2 < cnt) ? csrc[beg + i2] : -1;   // prefetch next index
      if (e >= 0){
        uint4 p = hs[(size_t)e*4 + q];
        HU u0,u1,u2,u3; u0.u=p.x; u1.u=p.y; u2.u=p.z; u3.u=p.w;
        a[0]+=(float)u0.h[0]; a[1]+=(float)u0.h[1];
        a[2]+=(float)u1.h[0]; a[3]+=(float)u1.h[1];
        a[4]+=(float)u2.h[0]; a[5]+=(float)u2.h[1];
        a[6]+=(float)u3.h[0]; a[7]+=(float)u3.h[1];
      }
      e = e2; i = i2;
    }
#pragma unroll
    for (int k=0;k<8;k++){
      a[k] += __shfl_xor(a[k], 4);
      a[k] += __shfl_xor(a[k], 8);
    }
    if (s == 0 && vok){
      float nd = nD[v];
      uint4 hp = h0[(size_t)v*4 + q];
      HU u0,u1,u2,u3; u0.u=hp.x; u1.u=hp.y; u2.u=hp.z; u3.u=hp.w;
      float r[8];
      r[0]=0.9f*nd*a[0]+0.1f*(float)u0.h[0]; r[1]=0.9f*nd*a[1]+0.1f*(float)u0.h[1];
      r[2]=0.9f*nd*a[2]+0.1f*(float)u1.h[0]; r[3]=0.9f*nd*a[3]+0.1f*(float)u1.h[1];
      r[4]=0.9f*nd*a[4]+0.1f*(float)u2.h[0]; r[5]=0.9f*nd*a[5]+0.1f*(float)u2.h[1];
      r[6]=0.9f*nd*a[6]+0.1f*(float)u3.h[0]; r[7]=0.9f*nd*a[7]+0.1f*(float)u3.h[1];
      if (LAST){
        out4[(size_t)v*8 + q*2]     = make_float4(r[0],r[1],r[2],r[3]);
        out4[(size_t)v*8 + q*2 + 1] = make_float4(r[4],r[5],r[6],r[7]);
      } else {
        float ns = nS[v];
        HU o0,o1,o2,o3;
        o0.h[0]=(_Float16)(ns*r[0]); o0.h[1]=(_Float16)(ns*r[1]);
        o1.h[0]=(_Float16)(ns*r[2]); o1.h[1]=(_Float16)(ns*r[3]);
        o2.h[0]=(_Float16)(ns*r[4]); o2.h[1]=(_Float16)(ns*r[5]);
        o3.h[0]=(_Float16)(ns*r[6]); o3.h[1]=(_Float16)(ns*r[7]);
        uint4 o; o.x=o0.u; o.y=o1.u; o.z=o2.u; o.w=o3.u;
        hs_out[(size_t)v*4 + q] = o;
      }
    }
  }
}

extern "C" void kernel_launch(void* const* d_in, const int* in_sizes, int n_in,
                              void* d_out, int out_size, void* d_ws, size_t ws_size,
                              hipStream_t stream)
{
  const float* feats = (const float*)d_in[0];
  const int*   src   = (const int*)d_in[1];
  const int*   dst   = (const int*)d_in[2];
  const float* W1    = (const float*)d_in[3];
  const float* b1    = (const float*)d_in[4];
  const float* W2    = (const float*)d_in[5];
  const float* b2    = (const float*)d_in[6];
  float* out = (float*)d_out;

  char* ws = (char*)d_ws;
  size_t off = 0;
  auto alloc = [&](size_t bytes) -> void* {
    void* p = ws + off;
    off = (off + bytes + 255) & ~(size_t)255;
    return p;
  };
  _Float16* W1T = (_Float16*)alloc((size_t)DIN*DH*2);
  _Float16* W2T = (_Float16*)alloc((size_t)DH*DOUT*2);
  int*   pO     = (int*)  alloc((size_t)HNS*NN*4);
  int*   pI     = (int*)  alloc((size_t)HNS*NN*4);
  int*   degI   = (int*)  alloc((size_t)NN*4);
  float* nS     = (float*)alloc((size_t)NN*4);
  float* nD     = (float*)alloc((size_t)NN*4);
  int*   offs   = (int*)  alloc((size_t)NN*4);
  int*   bsum   = (int*)  alloc(512);
  int*   boff   = (int*)  alloc(512);
  int*   csrc   = (int*)  alloc((size_t)EE*4);
  _Float16* h0h = (_Float16*)alloc((size_t)NN*DOUT*2);
  _Float16* hs0 = (_Float16*)alloc((size_t)NN*DOUT*2);
  unsigned int* pA = (unsigned int*)alloc((size_t)NN*DOUT*2);
  unsigned int* pB = (unsigned int*)alloc((size_t)NN*DOUT*2);

  conv_w1<<<(DIN*DH+255)/256, 256, 0, stream>>>(W1, W1T);
  conv_w2<<<(DH*DOUT+255)/256, 256, 0, stream>>>(W2, W2T);

  gemm1_hist<<<2*HISTB + 2*((NN+63)/64), 256, 0, stream>>>(
      feats, W1T, b1, out, src, dst, pO, pI);

  combine<<<(NN+255)/256, 256, 0, stream>>>(pO, pI, degI, nS, nD);
  int nb = (NN+1023)/1024;
  scan1<<<nb, 1024, 0, stream>>>(degI, offs, bsum);
  scan2<<<1, 128, 0, stream>>>(bsum, boff, nb);
  scan3<<<(NN+255)/256, 256, 0, stream>>>(offs, boff);

  fused2<<<HISTB + (NN+255)/256, 256, 0, stream>>>(out, W2T, b2, nS, h0h, hs0,
                                                   src, dst, pI, offs, csrc);

  float4* out4 = (float4*)(out + (size_t)NN*DH);
  const uint4* cur = (const uint4*)hs0;
  const uint4* h0u = (const uint4*)h0h;
  for (int it=0; it<9; ++it){
    uint4* nxt = (uint4*)((it&1)? pB : pA);
    propC<false><<<3125, 256, 0, stream>>>(cur, h0u, nxt, nullptr, offs, degI, csrc, nS, nD);
    cur = nxt;
  }
  propC<true><<<3125, 256, 0, stream>>>(cur, h0u, nullptr, out4, offs, degI, csrc, nS, nD);
}

// Round 15
// 512.800 us; speedup vs baseline: 1.2583x; 1.2583x over previous
//
#include <hip/hip_runtime.h>

#define NN 100000
#define EE 1600000
#define DIN 512
#define DH 256
#define DOUT 32
#define RANKB 512
#define HNR 25
#define HNS 16
#define RBH 4000      // NN/HNR bins per range
#define HES 100000    // EE/HNS edges per slice
#define HISTB (HNR*HNS)

typedef _Float16 h16x8 __attribute__((ext_vector_type(8)));
typedef _Float16 h16x4 __attribute__((ext_vector_type(4)));
typedef float f32x4 __attribute__((ext_vector_type(4)));

union HU { unsigned int u; _Float16 h[2]; };

// ---------- weight transpose + fp16 convert ----------
__global__ __launch_bounds__(256) void conv_w1(const float* __restrict__ W1, _Float16* __restrict__ W1T){
  int i = blockIdx.x*256 + threadIdx.x;
  if (i < DIN*DH){
    int c = i >> 9, k = i & 511;          // W1T[c][k] = W1[k][c]
    W1T[i] = (_Float16)W1[k*DH + c];
  }
}
__global__ __launch_bounds__(256) void conv_w2(const float* __restrict__ W2, _Float16* __restrict__ W2T){
  int i = blockIdx.x*256 + threadIdx.x;
  if (i < DH*DOUT){
    int c = i >> 8, k = i & 255;          // W2T[c][k] = W2[k][c]
    W2T[i] = (_Float16)W2[k*DOUT + c];
  }
}

// ---------- fused: rank-atomic blocks + degO LDS-hist blocks + LDS gemm1 ----------
__global__ __launch_bounds__(256) void gemm1_deg(
    const float* __restrict__ feats, const _Float16* __restrict__ W1T,
    const float* __restrict__ b1, float* __restrict__ h1,
    const int* __restrict__ src, const int* __restrict__ dst,
    int* __restrict__ cnt, int* __restrict__ pO, int* __restrict__ rnk)
{
  __shared__ __align__(16) int smem[RBH];          // 16000 B; gemm aliases 15360 B of it
  const int bid = blockIdx.x;
  const int tid = threadIdx.x;

  if (bid < RANKB){
    for (int i = bid*256 + tid; i < EE; i += RANKB*256)
      rnk[i] = atomicAdd(&cnt[dst[i]], 1);
    return;
  }
  if (bid < RANKB + HISTB){
    const int hb = bid - RANKB;
    const int r = hb / HNS, s = hb % HNS;
    const int r0 = r * RBH;
    for (int j = tid; j < RBH; j += 256) smem[j] = 0;
    __syncthreads();
    const int4* s4 = reinterpret_cast<const int4*>(src + (size_t)s*HES);
    for (int i = tid; i < HES/8; i += 256){
      int4 a = s4[2*i], b = s4[2*i+1];
      int k;
      k = a.x - r0; if ((unsigned)k < RBH) atomicAdd(&smem[k], 1);
      k = a.y - r0; if ((unsigned)k < RBH) atomicAdd(&smem[k], 1);
      k = a.z - r0; if ((unsigned)k < RBH) atomicAdd(&smem[k], 1);
      k = a.w - r0; if ((unsigned)k < RBH) atomicAdd(&smem[k], 1);
      k = b.x - r0; if ((unsigned)k < RBH) atomicAdd(&smem[k], 1);
      k = b.y - r0; if ((unsigned)k < RBH) atomicAdd(&smem[k], 1);
      k = b.z - r0; if ((unsigned)k < RBH) atomicAdd(&smem[k], 1);
      k = b.w - r0; if ((unsigned)k < RBH) atomicAdd(&smem[k], 1);
    }
    __syncthreads();
    for (int j = tid; j < RBH; j += 256) pO[(size_t)s*NN + r0 + j] = smem[j];
    return;
  }

  // ---- gemm1 (R3 engine), LDS aliased onto smem ----
  _Float16 (*At)[40] = reinterpret_cast<_Float16(*)[40]>(smem);
  _Float16 (*Bt)[40] = reinterpret_cast<_Float16(*)[40]>(reinterpret_cast<char*>(smem) + 5120);
  const int gid  = bid - (RANKB + HISTB);
  const int col0 = (gid & 1) * 128;
  const int row0 = (gid >> 1) * 64;

  const int lane = tid & 63, wave = tid >> 6;
  const int wr = wave >> 1, wc = wave & 1;
  const int l15 = lane & 15, kg = lane >> 4;
  const int arow = tid >> 2, aseg = (tid & 3) * 8;
  const int bcol = tid >> 1, bseg = (tid & 1) * 16;
  const bool aok = (row0 + arow) < NN;
  const float* aP = feats + (size_t)(row0+arow)*DIN + aseg;
  const _Float16* bP = W1T + (size_t)(col0+bcol)*DIN + bseg;

  f32x4 acc[2][4];
#pragma unroll
  for (int m=0;m<2;m++)
#pragma unroll
    for (int n=0;n<4;n++){ acc[m][n][0]=0.f; acc[m][n][1]=0.f; acc[m][n][2]=0.f; acc[m][n][3]=0.f; }

  float4 fa0 = make_float4(0,0,0,0), fa1 = make_float4(0,0,0,0);
  h16x8 fb0, fb1;
  if (aok){
    fa0 = *reinterpret_cast<const float4*>(aP);
    fa1 = *reinterpret_cast<const float4*>(aP + 4);
  }
  fb0 = *reinterpret_cast<const h16x8*>(bP);
  fb1 = *reinterpret_cast<const h16x8*>(bP + 8);

  for (int t=0; t<16; ++t){
    {
      h16x4 v0, v1;
      v0[0]=(_Float16)fa0.x; v0[1]=(_Float16)fa0.y; v0[2]=(_Float16)fa0.z; v0[3]=(_Float16)fa0.w;
      v1[0]=(_Float16)fa1.x; v1[1]=(_Float16)fa1.y; v1[2]=(_Float16)fa1.z; v1[3]=(_Float16)fa1.w;
      *reinterpret_cast<h16x4*>(&At[arow][aseg])   = v0;
      *reinterpret_cast<h16x4*>(&At[arow][aseg+4]) = v1;
      *reinterpret_cast<h16x8*>(&Bt[bcol][bseg])   = fb0;
      *reinterpret_cast<h16x8*>(&Bt[bcol][bseg+8]) = fb1;
    }
    __syncthreads();
    if (t < 15){
      int k0 = (t+1)*32;
      if (aok){
        fa0 = *reinterpret_cast<const float4*>(aP + k0);
        fa1 = *reinterpret_cast<const float4*>(aP + k0 + 4);
      }
      fb0 = *reinterpret_cast<const h16x8*>(bP + k0);
      fb1 = *reinterpret_cast<const h16x8*>(bP + k0 + 8);
    }
    h16x8 af[2], bfr[4];
#pragma unroll
    for (int m=0;m<2;m++) af[m]  = *reinterpret_cast<const h16x8*>(&At[wr*32 + m*16 + l15][kg*8]);
#pragma unroll
    for (int n=0;n<4;n++) bfr[n] = *reinterpret_cast<const h16x8*>(&Bt[wc*64 + n*16 + l15][kg*8]);
#pragma unroll
    for (int m=0;m<2;m++)
#pragma unroll
      for (int n=0;n<4;n++)
        acc[m][n] = __builtin_amdgcn_mfma_f32_16x16x32_f16(af[m], bfr[n], acc[m][n], 0, 0, 0);
    __syncthreads();
  }
  const int rb = kg*4;
#pragma unroll
  for (int n=0;n<4;n++){
    int col = col0 + wc*64 + n*16 + l15;
    float bias = b1[col];
#pragma unroll
    for (int m=0;m<2;m++){
#pragma unroll
      for (int j=0;j<4;j++){
        int g = row0 + wr*32 + m*16 + rb + j;
        if (g < NN) h1[(size_t)g*DH + col] = acc[m][n][j] + bias;
      }
    }
  }
}

// ---------- combine: degO partial sum -> nS; cnt -> degI, nD ----------
__global__ __launch_bounds__(256) void combine(
    const int* __restrict__ pO, const int* __restrict__ cnt,
    int* __restrict__ degI, float* __restrict__ nS, float* __restrict__ nD)
{
  int v = blockIdx.x*256 + threadIdx.x;
  if (v >= NN) return;
  int so = 0;
#pragma unroll
  for (int s=0;s<HNS;s++) so += pO[(size_t)s*NN + v];
  int si = cnt[v];
  degI[v] = si;
  nS[v] = rsqrtf((float)(so > 0 ? so : 1));
  nD[v] = rsqrtf((float)(si > 0 ? si : 1));
}

// ---------- scans (offs = exclusive prefix of degI) ----------
__global__ __launch_bounds__(1024) void scan1(const int* __restrict__ degI, int* __restrict__ offs, int* __restrict__ bsum){
  __shared__ int sm[1024];
  int t = threadIdx.x;
  int g = blockIdx.x*1024 + t;
  int v = (g < NN) ? degI[g] : 0;
  sm[t] = v; __syncthreads();
  for (int o=1;o<1024;o<<=1){
    int a = (t>=o)? sm[t-o] : 0;
    __syncthreads();
    sm[t] += a;
    __syncthreads();
  }
  if (g < NN) offs[g] = sm[t] - v;
  if (t == 1023) bsum[blockIdx.x] = sm[t];
}
__global__ __launch_bounds__(128) void scan2(const int* __restrict__ bsum, int* __restrict__ boff, int nb){
  __shared__ int sm[128];
  int t = threadIdx.x;
  int v = (t < nb)? bsum[t] : 0;
  sm[t] = v; __syncthreads();
  for (int o=1;o<128;o<<=1){
    int a = (t>=o)? sm[t-o] : 0;
    __syncthreads();
    sm[t] += a;
    __syncthreads();
  }
  if (t < nb) boff[t] = sm[t] - v;
}
__global__ __launch_bounds__(256) void scan3(int* __restrict__ offs, const int* __restrict__ boff){
  int i = blockIdx.x*256 + threadIdx.x;
  if (i < NN) offs[i] += boff[i >> 10];
}

// ---------- fused2: LDS-free GEMM2 + atomic-free CSR scatter ----------
__global__ __launch_bounds__(256) void fused2(
    const float* __restrict__ h1, const _Float16* __restrict__ W2T,
    const float* __restrict__ b2, const float* __restrict__ nS,
    _Float16* __restrict__ h0h, _Float16* __restrict__ hsh,
    const int* __restrict__ src, const int* __restrict__ dst,
    const int* __restrict__ offs, const int* __restrict__ rnk,
    int* __restrict__ csrc)
{
  const int bid = blockIdx.x;
  const int tid = threadIdx.x;
  if (bid < 1024){
    for (int i = bid*256 + tid; i < EE; i += 1024*256){
      csrc[offs[dst[i]] + rnk[i]] = src[i];
    }
    return;
  }
  const int gid = bid - 1024;
  const int row0 = gid * 256;
  const int lane = tid & 63, wave = tid >> 6;
  const int l15 = lane & 15, kg = lane >> 4;

  f32x4 acc[4][2];
#pragma unroll
  for (int m=0;m<4;m++)
#pragma unroll
    for (int n=0;n<2;n++){ acc[m][n][0]=0.f; acc[m][n][1]=0.f; acc[m][n][2]=0.f; acc[m][n][3]=0.f; }

  const float* aP[4]; bool aok[4];
#pragma unroll
  for (int m=0;m<4;m++){
    int r = row0 + wave*64 + m*16 + l15;
    aok[m] = (r < NN);
    aP[m] = h1 + (size_t)r*DH + kg*8;
  }
  const _Float16* bP[2];
#pragma unroll
  for (int n=0;n<2;n++)
    bP[n] = W2T + (size_t)(n*16 + l15)*DH + kg*8;

  for (int t=0; t<8; ++t){
    const int k0 = t*32;
    h16x8 bf[2], af[4];
#pragma unroll
    for (int n=0;n<2;n++) bf[n] = *reinterpret_cast<const h16x8*>(bP[n] + k0);
#pragma unroll
    for (int m=0;m<4;m++){
      float4 x = make_float4(0,0,0,0), y = make_float4(0,0,0,0);
      if (aok[m]){
        x = *reinterpret_cast<const float4*>(aP[m] + k0);
        y = *reinterpret_cast<const float4*>(aP[m] + k0 + 4);
      }
      h16x8 v;
      v[0]=(_Float16)fmaxf(x.x,0.f); v[1]=(_Float16)fmaxf(x.y,0.f);
      v[2]=(_Float16)fmaxf(x.z,0.f); v[3]=(_Float16)fmaxf(x.w,0.f);
      v[4]=(_Float16)fmaxf(y.x,0.f); v[5]=(_Float16)fmaxf(y.y,0.f);
      v[6]=(_Float16)fmaxf(y.z,0.f); v[7]=(_Float16)fmaxf(y.w,0.f);
      af[m] = v;
    }
#pragma unroll
    for (int m=0;m<4;m++)
#pragma unroll
      for (int n=0;n<2;n++)
        acc[m][n] = __builtin_amdgcn_mfma_f32_16x16x32_f16(af[m], bf[n], acc[m][n], 0, 0, 0);
  }
  const int rb = kg*4;
#pragma unroll
  for (int n=0;n<2;n++){
    int col = n*16 + l15;
    float bias = b2[col];
#pragma unroll
    for (int m=0;m<4;m++){
#pragma unroll
      for (int j=0;j<4;j++){
        int g = row0 + wave*64 + m*16 + rb + j;
        if (g < NN){
          float val = acc[m][n][j] + bias;
          h0h[(size_t)g*DOUT + col] = (_Float16)val;
          hsh[(size_t)g*DOUT + col] = (_Float16)(nS[g] * val);
        }
      }
    }
  }
}

// ---------- prop: dwordx4 gather — 4 nodes x 4 slots x 4 feature-quads (~24us/iter) ----------
template<bool LAST>
__global__ __launch_bounds__(256) void propC(
    const uint4* __restrict__ hs, const uint4* __restrict__ h0,
    uint4* __restrict__ hs_out, float4* __restrict__ out4,
    const int* __restrict__ offs, const int* __restrict__ degI,
    const int* __restrict__ csrc,
    const float* __restrict__ nS, const float* __restrict__ nD)
{
  const int nw = gridDim.x * 4;
  const int wid = (blockIdx.x*256 + threadIdx.x) >> 6;
  const int lane = threadIdx.x & 63;
  const int n = lane >> 4;        // node in quad (bits 5:4)
  const int s = (lane >> 2) & 3;  // edge slot    (bits 3:2)
  const int q = lane & 3;         // feature quad (bits 1:0) -> 16B of row

  const int NQ = (NN + 3) / 4;
  for (int vq = wid; vq < NQ; vq += nw){
    const int v = vq*4 + n;
    const bool vok = (v < NN);
    int beg = 0, cnt = 0;
    if (vok){ beg = offs[v]; cnt = degI[v]; }
    float a[8];
#pragma unroll
    for (int k=0;k<8;k++) a[k]=0.f;

    int i = s;
    int e = (i < cnt) ? csrc[beg + i] : -1;
    while (__any(e >= 0)){
      int i2 = i + 4;
      int e2 = (i2 < cnt) ? csrc[beg + i2] : -1;   // prefetch next index
      if (e >= 0){
        uint4 p = hs[(size_t)e*4 + q];
        HU u0,u1,u2,u3; u0.u=p.x; u1.u=p.y; u2.u=p.z; u3.u=p.w;
        a[0]+=(float)u0.h[0]; a[1]+=(float)u0.h[1];
        a[2]+=(float)u1.h[0]; a[3]+=(float)u1.h[1];
        a[4]+=(float)u2.h[0]; a[5]+=(float)u2.h[1];
        a[6]+=(float)u3.h[0]; a[7]+=(float)u3.h[1];
      }
      e = e2; i = i2;
    }
#pragma unroll
    for (int k=0;k<8;k++){
      a[k] += __shfl_xor(a[k], 4);
      a[k] += __shfl_xor(a[k], 8);
    }
    if (s == 0 && vok){
      float nd = nD[v];
      uint4 hp = h0[(size_t)v*4 + q];
      HU u0,u1,u2,u3; u0.u=hp.x; u1.u=hp.y; u2.u=hp.z; u3.u=hp.w;
      float r[8];
      r[0]=0.9f*nd*a[0]+0.1f*(float)u0.h[0]; r[1]=0.9f*nd*a[1]+0.1f*(float)u0.h[1];
      r[2]=0.9f*nd*a[2]+0.1f*(float)u1.h[0]; r[3]=0.9f*nd*a[3]+0.1f*(float)u1.h[1];
      r[4]=0.9f*nd*a[4]+0.1f*(float)u2.h[0]; r[5]=0.9f*nd*a[5]+0.1f*(float)u2.h[1];
      r[6]=0.9f*nd*a[6]+0.1f*(float)u3.h[0]; r[7]=0.9f*nd*a[7]+0.1f*(float)u3.h[1];
      if (LAST){
        out4[(size_t)v*8 + q*2]     = make_float4(r[0],r[1],r[2],r[3]);
        out4[(size_t)v*8 + q*2 + 1] = make_float4(r[4],r[5],r[6],r[7]);
      } else {
        float ns = nS[v];
        HU o0,o1,o2,o3;
        o0.h[0]=(_Float16)(ns*r[0]); o0.h[1]=(_Float16)(ns*r[1]);
        o1.h[0]=(_Float16)(ns*r[2]); o1.h[1]=(_Float16)(ns*r[3]);
        o2.h[0]=(_Float16)(ns*r[4]); o2.h[1]=(_Float16)(ns*r[5]);
        o3.h[0]=(_Float16)(ns*r[6]); o3.h[1]=(_Float16)(ns*r[7]);
        uint4 o; o.x=o0.u; o.y=o1.u; o.z=o2.u; o.w=o3.u;
        hs_out[(size_t)v*4 + q] = o;
      }
    }
  }
}

extern "C" void kernel_launch(void* const* d_in, const int* in_sizes, int n_in,
                              void* d_out, int out_size, void* d_ws, size_t ws_size,
                              hipStream_t stream)
{
  const float* feats = (const float*)d_in[0];
  const int*   src   = (const int*)d_in[1];
  const int*   dst   = (const int*)d_in[2];
  const float* W1    = (const float*)d_in[3];
  const float* b1    = (const float*)d_in[4];
  const float* W2    = (const float*)d_in[5];
  const float* b2    = (const float*)d_in[6];
  float* out = (float*)d_out;

  char* ws = (char*)d_ws;
  size_t off = 0;
  auto alloc = [&](size_t bytes) -> void* {
    void* p = ws + off;
    off = (off + bytes + 255) & ~(size_t)255;
    return p;
  };
  _Float16* W1T = (_Float16*)alloc((size_t)DIN*DH*2);
  _Float16* W2T = (_Float16*)alloc((size_t)DH*DOUT*2);
  int*   cnt    = (int*)  alloc((size_t)NN*4);
  int*   pO     = (int*)  alloc((size_t)HNS*NN*4);
  int*   degI   = (int*)  alloc((size_t)NN*4);
  float* nS     = (float*)alloc((size_t)NN*4);
  float* nD     = (float*)alloc((size_t)NN*4);
  int*   offs   = (int*)  alloc((size_t)NN*4);
  int*   bsum   = (int*)  alloc(512);
  int*   boff   = (int*)  alloc(512);
  int*   rnk    = (int*)  alloc((size_t)EE*4);
  int*   csrc   = (int*)  alloc((size_t)EE*4);
  _Float16* h0h = (_Float16*)alloc((size_t)NN*DOUT*2);
  _Float16* hs0 = (_Float16*)alloc((size_t)NN*DOUT*2);
  unsigned int* pA = (unsigned int*)alloc((size_t)NN*DOUT*2);
  unsigned int* pB = (unsigned int*)alloc((size_t)NN*DOUT*2);

  hipMemsetAsync(cnt, 0, (size_t)NN*4, stream);

  conv_w1<<<(DIN*DH+255)/256, 256, 0, stream>>>(W1, W1T);
  conv_w2<<<(DH*DOUT+255)/256, 256, 0, stream>>>(W2, W2T);

  gemm1_deg<<<RANKB + HISTB + 2*((NN+63)/64), 256, 0, stream>>>(
      feats, W1T, b1, out, src, dst, cnt, pO, rnk);

  combine<<<(NN+255)/256, 256, 0, stream>>>(pO, cnt, degI, nS, nD);
  int nb = (NN+1023)/1024;
  scan1<<<nb, 1024, 0, stream>>>(degI, offs, bsum);
  scan2<<<1, 128, 0, stream>>>(bsum, boff, nb);
  scan3<<<(NN+255)/256, 256, 0, stream>>>(offs, boff);

  fused2<<<1024 + (NN+255)/256, 256, 0, stream>>>(out, W2T, b2, nS, h0h, hs0,
                                                  src, dst, offs, rnk, csrc);

  float4* out4 = (float4*)(out + (size_t)NN*DH);
  const uint4* cur = (const uint4*)hs0;
  const uint4* h0u = (const uint4*)h0h;
  for (int it=0; it<9; ++it){
    uint4* nxt = (uint4*)((it&1)? pB : pA);
    propC<false><<<3125, 256, 0, stream>>>(cur, h0u, nxt, nullptr, offs, degI, csrc, nS, nD);
    cur = nxt;
  }
  propC<true><<<3125, 256, 0, stream>>>(cur, h0u, nullptr, out4, offs, degI, csrc, nS, nD);
}